// Round 4
// baseline (106.543 us; speedup 1.0000x reference)
//
#include <hip/hip_runtime.h>

#define Bdim 4
#define Cdim 128
#define Hdim 96
#define Wdim 96
#define HW   (Hdim*Wdim)        // 9216
#define NOC  18                 // rot conv output channels
#define PADH 98                 // rows: true row r -> padded row r+1
#define PADW 104                // cols: true col c -> padded col c+3 (16B-aligned rows)

// ---------------------------------------------------------------------------
// Kernel 1: zero-padded copy of x into workspace. offset (+1,+3).
// ---------------------------------------------------------------------------
__global__ __launch_bounds__(256) void pad_kernel(const float* __restrict__ x,
                                                  float* __restrict__ xpad) {
    int idx = blockIdx.x * 256 + threadIdx.x;
    const int total = Bdim * Cdim * PADH * PADW;
    if (idx >= total) return;
    int col  = idx % PADW;
    int rest = idx / PADW;
    int row  = rest % PADH;
    int bc   = rest / PADH;
    int tr = row - 1;
    int tc = col - 3;
    float v = 0.f;
    if ((unsigned)tr < (unsigned)Hdim && (unsigned)tc < (unsigned)Wdim)
        v = x[(size_t)bc * HW + tr * Wdim + tc];
    xpad[idx] = v;
}

// ---------------------------------------------------------------------------
// Kernel 2: rot partial conv — ZERO LDS.
// Block = 384 threads (64, 6). threadIdx.y = oc-group (3 oc), wave-uniform ->
// weights ride the scalar k-cache pipe (s_load), freeing LDS entirely.
// Thread = 2w x 3h pixel quad. Per cl: 10 dwordx2 x-loads (prefetched), 27
// scalar weight floats, 162 FMA. 4608 waves total (4.5/SIMD).
// rot_part[chunk][b][oc][HW].
// ---------------------------------------------------------------------------
template<int CC>
__global__ __launch_bounds__(384) void conv_kernel(const float* __restrict__ xpad,
                                                   const float* __restrict__ rot_w,
                                                   float* __restrict__ rot_part) {
    const int tid   = threadIdx.x;       // 0..63
    const int grp   = threadIdx.y;       // 0..5
    const int o0    = grp * 3;
    const int chunk = blockIdx.z;
    const int b     = blockIdx.y;
    const int c0    = chunk * CC;
    const int tile  = blockIdx.x;        // 0..23
    const int tileh = (tile / 3) * 12;
    const int tilew = (tile % 3) * 32;
    const int txw = tid & 15;
    const int txh = tid >> 4;
    const int w0 = tilew + 2 * txw;      // true col of left pixel (even)
    const int h0 = tileh + 3 * txh;      // true row of top pixel

    // x window: true rows h0-1..h0+3 -> padded rows h0..h0+4;
    //           true cols w0-1..w0+2 -> padded cols w0+2..w0+5 (8B aligned)
    const float* xb = xpad + ((size_t)(b * Cdim + c0) * PADH + h0) * PADW + (w0 + 2);
    const float* wb = rot_w + (size_t)c0 * 9;   // + o*(Cdim*9) + cl*9 + k

    float acc[3][6];
#pragma unroll
    for (int o = 0; o < 3; ++o)
#pragma unroll
        for (int p = 0; p < 6; ++p) acc[o][p] = 0.f;

    float xv[5][4];
#pragma unroll
    for (int r = 0; r < 5; ++r) {
        float2 a0 = *reinterpret_cast<const float2*>(xb + r * PADW);
        float2 a1 = *reinterpret_cast<const float2*>(xb + r * PADW + 2);
        xv[r][0] = a0.x; xv[r][1] = a0.y; xv[r][2] = a1.x; xv[r][3] = a1.y;
    }

    for (int cl = 0; cl < CC; ++cl) {
        float xn[5][4];
        if (cl + 1 < CC) {
            const float* xr = xb + (size_t)(cl + 1) * PADH * PADW;
#pragma unroll
            for (int r = 0; r < 5; ++r) {
                float2 a0 = *reinterpret_cast<const float2*>(xr + r * PADW);
                float2 a1 = *reinterpret_cast<const float2*>(xr + r * PADW + 2);
                xn[r][0] = a0.x; xn[r][1] = a0.y; xn[r][2] = a1.x; xn[r][3] = a1.y;
            }
        }
        const float* wc = wb + cl * 9;
#pragma unroll
        for (int oo = 0; oo < 3; ++oo) {
            const float* wp = wc + (size_t)(o0 + oo) * (Cdim * 9);  // wave-uniform
            float wv0 = wp[0], wv1 = wp[1], wv2 = wp[2];
            float wv3 = wp[3], wv4 = wp[4], wv5 = wp[5];
            float wv6 = wp[6], wv7 = wp[7], wv8 = wp[8];
#pragma unroll
            for (int r = 0; r < 3; ++r) {
#pragma unroll
                for (int cc2 = 0; cc2 < 2; ++cc2) {
                    float a = acc[oo][r * 2 + cc2];
                    a = fmaf(xv[r + 0][cc2 + 0], wv0, a);
                    a = fmaf(xv[r + 0][cc2 + 1], wv1, a);
                    a = fmaf(xv[r + 0][cc2 + 2], wv2, a);
                    a = fmaf(xv[r + 1][cc2 + 0], wv3, a);
                    a = fmaf(xv[r + 1][cc2 + 1], wv4, a);
                    a = fmaf(xv[r + 1][cc2 + 2], wv5, a);
                    a = fmaf(xv[r + 2][cc2 + 0], wv6, a);
                    a = fmaf(xv[r + 2][cc2 + 1], wv7, a);
                    a = fmaf(xv[r + 2][cc2 + 2], wv8, a);
                    acc[oo][r * 2 + cc2] = a;
                }
            }
        }
#pragma unroll
        for (int r = 0; r < 5; ++r)
#pragma unroll
            for (int j = 0; j < 4; ++j)
                xv[r][j] = xn[r][j];
    }

    float* dst = rot_part + ((size_t)(chunk * Bdim + b) * NOC + o0) * HW + h0 * Wdim + w0;
#pragma unroll
    for (int oo = 0; oo < 3; ++oo)
#pragma unroll
        for (int r = 0; r < 3; ++r)
            *reinterpret_cast<float2*>(dst + (size_t)oo * HW + r * Wdim) =
                make_float2(acc[oo][r * 2], acc[oo][r * 2 + 1]);
}

// ---------------------------------------------------------------------------
// Kernel 3: reduce conv partials (+bias) -> bilinear coefficient quads.
// coefq[(b*9+t)*HW+hw] = (q00, q01, q10, float(h0*3+w0)); q11 = 1-q00-q01-q10.
// ---------------------------------------------------------------------------
template<int NCH>
__global__ __launch_bounds__(256) void coef_kernel(const float* __restrict__ rot_part,
                                                   const float* __restrict__ rot_b,
                                                   float4* __restrict__ coefq) {
    int idx = blockIdx.x * 256 + threadIdx.x;   // 0..36863
    int b  = idx / HW;
    int hw = idx % HW;
    int t0 = blockIdx.y * 3;
#pragma unroll
    for (int tt = 0; tt < 3; ++tt) {
        int t = t0 + tt;
        int i = t / 3, j = t % 3;
        float ch = rot_b[2 * t + 0] + (0.5f + (float)i);
        float cw = rot_b[2 * t + 1] + (0.5f + (float)j);
#pragma unroll
        for (int k = 0; k < NCH; ++k) {
            const float* rp = rot_part + ((size_t)(k * Bdim + b) * NOC) * HW + hw;
            ch += rp[(size_t)(2 * t + 0) * HW];
            cw += rp[(size_t)(2 * t + 1) * HW];
        }
        ch = fminf(fmaxf(ch, 0.f), 3.f);
        cw = fminf(fmaxf(cw, 0.f), 3.f);
        float h0f = floorf(ch), w0f = floorf(cw);
        float lh = ch - h0f, lw = cw - w0f;
        int h0 = (int)h0f, w0 = (int)w0f;
        float bh0 = 1.f - lh;
        float aw0 = 1.f - lw;
        if (h0 >= 3) { h0 = 2; bh0 = 0.f; }
        if (w0 >= 3) { w0 = 2; aw0 = 0.f; }
        float4 cf;
        cf.x = aw0 * bh0;                 // q00 -> W[h0][w0]
        cf.y = (1.f - aw0) * bh0;         // q01 -> W[h0][w0+1]
        cf.z = aw0 * (1.f - bh0);         // q10 -> W[h0+1][w0]
        cf.w = (float)(h0 * 3 + w0);      // table index
        coefq[(size_t)(b * 9 + t) * HW + hw] = cf;
    }
}

// ---------------------------------------------------------------------------
// Kernel 4: apply. Thread = 1 pixel, loops 32 channels (ty picks c-range).
// Per-c packed bilinear quad table wq[c][9] (float4) in LDS, one b128 per tap.
// ---------------------------------------------------------------------------
__global__ __launch_bounds__(256) void apply_kernel(const float* __restrict__ xpad,
                                                    const float4* __restrict__ coefq,
                                                    const float* __restrict__ weight,
                                                    float* __restrict__ out) {
    __shared__ float4 wq[Cdim * 9];
    int tid = threadIdx.y * 64 + threadIdx.x;
    for (int i = tid; i < Cdim * 9; i += 256) {
        int c = i / 9, t = i - c * 9;
        int r = t / 3, s = t - r * 3;
        const float* wb = weight + (size_t)c * 16 + r * 4 + s;
        wq[i] = make_float4(wb[0], wb[1], wb[4], wb[5]);
    }
    __syncthreads();

    int px = blockIdx.x * 64 + threadIdx.x;   // 0..36863
    int b  = px / HW;
    int hw = px % HW;
    int h  = hw / Wdim;
    int wc = hw % Wdim;

    float q00[9], q01[9], q10[9], q11[9];
    int lidx[9];
#pragma unroll
    for (int t = 0; t < 9; ++t) {
        float4 cf = coefq[(size_t)(b * 9 + t) * HW + hw];
        q00[t] = cf.x;
        q01[t] = cf.y;
        q10[t] = cf.z;
        q11[t] = 1.f - cf.x - cf.y - cf.z;
        lidx[t] = (int)cf.w;
    }

    int c0 = threadIdx.y * 32;
    // tap (di,dj) reads true (h+di-1, w+dj-1) -> padded (h+di, w+dj+2)
    const float* xb = xpad + ((size_t)(b * Cdim + c0) * PADH + h) * PADW + (wc + 2);
    float* ob = out + ((size_t)(b * Cdim + c0)) * HW + hw;

#pragma unroll 2
    for (int k = 0; k < 32; ++k) {
        int c = c0 + k;
        float acc = 0.f;
#pragma unroll
        for (int t = 0; t < 9; ++t) {
            float4 g = wq[c * 9 + lidx[t]];
            float ws = q00[t] * g.x;
            ws = fmaf(q01[t], g.y, ws);
            ws = fmaf(q10[t], g.z, ws);
            ws = fmaf(q11[t], g.w, ws);
            acc = fmaf(ws, xb[(t / 3) * PADW + (t % 3)], acc);
        }
        ob[(size_t)k * HW] = acc;
        xb += (size_t)PADH * PADW;
    }
}

// ---------------------------------------------------------------------------
extern "C" void kernel_launch(void* const* d_in, const int* in_sizes, int n_in,
                              void* d_out, int out_size, void* d_ws, size_t ws_size,
                              hipStream_t stream) {
    const float* x      = (const float*)d_in[0];
    const float* rot_w  = (const float*)d_in[1];
    const float* rot_b  = (const float*)d_in[2];
    const float* weight = (const float*)d_in[3];
    float* out = (float*)d_out;

    char* ws = (char*)d_ws;
    const size_t xpad_n  = (size_t)Bdim * Cdim * PADH * PADW;   // 5,218,304 floats
    const size_t coefq_n = (size_t)Bdim * 9 * HW;               // 331,776 float4

    auto align256 = [](size_t v) { return ((v + 255) / 256) * 256; };
    size_t off_rot = align256(xpad_n * 4);

    const size_t rotp8 = (size_t)8 * Bdim * NOC * HW * 4;
    const size_t need8 = off_rot + align256(rotp8) + coefq_n * 16;

    float* xpad     = (float*)ws;
    float* rot_part = (float*)(ws + off_rot);

    const int pad_total = Bdim * Cdim * PADH * PADW;
    pad_kernel<<<(pad_total + 255) / 256, 256, 0, stream>>>(x, xpad);

    if (ws_size >= need8) {
        float4* coefq = (float4*)(ws + off_rot + align256(rotp8));
        conv_kernel<16><<<dim3(24, Bdim, 8), dim3(64, 6), 0, stream>>>(xpad, rot_w, rot_part);
        coef_kernel<8><<<dim3(Bdim * HW / 256, 3), 256, 0, stream>>>(rot_part, rot_b, coefq);
        apply_kernel<<<dim3(Bdim * HW / 64), dim3(64, 4), 0, stream>>>(xpad, coefq, weight, out);
    } else {
        const size_t rotp4 = (size_t)4 * Bdim * NOC * HW * 4;
        float4* coefq = (float4*)(ws + off_rot + align256(rotp4));
        conv_kernel<32><<<dim3(24, Bdim, 4), dim3(64, 6), 0, stream>>>(xpad, rot_w, rot_part);
        coef_kernel<4><<<dim3(Bdim * HW / 256, 3), 256, 0, stream>>>(rot_part, rot_b, coefq);
        apply_kernel<<<dim3(Bdim * HW / 64), dim3(64, 4), 0, stream>>>(xpad, coefq, weight, out);
    }
}

// Round 5
// 72.310 us; speedup vs baseline: 1.4734x; 1.4734x over previous
//
#include <hip/hip_runtime.h>

#define Bdim 4
#define Cdim 128
#define Hdim 96
#define Wdim 96
#define HW   (Hdim*Wdim)        // 9216
#define NOC  18                 // rot conv output channels
#define PADH 98                 // fp32 pad rows: true r -> r+1
#define PADW 104                // fp32 pad cols: true c -> c+3 (16B-aligned rows)

typedef __attribute__((ext_vector_type(8))) short bf16x8;
typedef __attribute__((ext_vector_type(4))) float f32x4;

__device__ inline short f2bf(float f) {          // round-to-nearest-even bf16
    unsigned u = __float_as_uint(f);
    unsigned r = (u + 0x7FFFu + ((u >> 16) & 1u)) >> 16;
    return (short)r;
}

// ---------------------------------------------------------------------------
// Kernel 1 (prep): one fused kernel, 4 block roles.
//  [0,768)    interior: (b, h, c-half). LDS-transpose 64c x 96w ->
//             bf16 NHWC xnh[b][h+1][w+1][c] AND fp32 NCHW xpad interior.
//  [768,776)  zero NHWC halo rows r=0,97.
//  [776,920)  repack rot_w -> wpk[mt][tap][chunk][lane][8] bf16 A-fragments.
//  [920,1432) zero fp32 xpad borders (per (b,c): rows 0/97 + cols 0-2,99-103).
// ---------------------------------------------------------------------------
__global__ __launch_bounds__(256) void prep_kernel(const float* __restrict__ x,
                                                   const float* __restrict__ rot_w,
                                                   float* __restrict__ xpad,
                                                   short* __restrict__ xnh,
                                                   short* __restrict__ wpk) {
    __shared__ short ldsT[96 * 72];   // [w][c_local], stride 72 (144B, 16B-aligned)
    const int bid = blockIdx.x;
    const int t   = threadIdx.x;

    if (bid < 768) {
        int b = bid / 192;
        int h = (bid / 2) % 96;
        int chalf = bid & 1;
        int c0 = chalf * 64;
        const float* xs = x + ((size_t)(b * Cdim + c0) * Hdim + h) * Wdim;
        float* xf = xpad + ((size_t)(b * Cdim + c0) * PADH + (h + 1)) * PADW + 3;
#pragma unroll
        for (int i = 0; i < 24; ++i) {
            int idx = i * 256 + t;           // 0..6143 = 64c x 96w
            int w  = idx % 96;
            int ci = idx / 96;
            float v = xs[(size_t)ci * HW + w];
            ldsT[w * 72 + ci] = f2bf(v);
            xf[(size_t)ci * (PADH * PADW) + w] = v;
        }
        __syncthreads();
        short* dst = xnh + (((size_t)b * 98 + (h + 1)) * 98 + 1) * 128 + c0;
#pragma unroll
        for (int j = 0; j < 3; ++j) {
            int idx = j * 256 + t;           // 0..767 = 96w x 8 c-groups
            int c8 = idx % 8;
            int w  = idx / 8;
            bf16x8 v = *(const bf16x8*)&ldsT[w * 72 + c8 * 8];
            *(bf16x8*)(dst + (size_t)w * 128 + c8 * 8) = v;
        }
    } else if (bid < 776) {
        int z = bid - 768;
        int b = z / 2;
        int r = (z & 1) ? 97 : 0;
        short* base = xnh + ((size_t)b * 98 + r) * 98 * 128;
        bf16x8 zero = {0,0,0,0,0,0,0,0};
        for (int i = t; i < 1568; i += 256)      // 1568*8 = 98*128
            ((bf16x8*)base)[i] = zero;
    } else if (bid < 920) {
        int f = (bid - 776) * 256 + t;           // 0..36863
        int e    = f & 7;
        int l    = (f >> 3) & 63;
        int ch   = (f >> 9) & 3;
        int tap  = (f >> 11) % 9;
        int mt   = f / 18432;
        int oc = mt * 16 + (l & 15);
        int c  = ch * 32 + (l >> 4) * 8 + e;
        float v = (oc < NOC) ? rot_w[(size_t)oc * (Cdim * 9) + c * 9 + tap] : 0.f;
        wpk[f] = f2bf(v);
    } else {
        int bi = bid - 920;                      // 0..511 -> (b,c)
        float* base = xpad + (size_t)bi * PADH * PADW;
        for (int i = t; i < 976; i += 256) {
            int r, col;
            if (i < 208) { r = (i / 104) * 97; col = i % 104; }
            else {
                int j = i - 208;
                r = 1 + j / 8;
                int k8 = j % 8;
                col = (k8 < 3) ? k8 : 96 + k8;   // cols 0,1,2,99..103
            }
            base[r * PADW + col] = 0.f;
        }
    }
}

// ---------------------------------------------------------------------------
// Kernel 2: conv via bf16 MFMA implicit GEMM.
// Wave = 16 pixels (one n-tile) x all 18(->32) oc. K = tap(9) x c-chunk(4) x 32.
// wpk staged in LDS (72KB); B-frags direct global dwordx4 (L1, 9x tap reuse).
// rot[b][oc][HW] fp32, complete (no partials).
// ---------------------------------------------------------------------------
__global__ __launch_bounds__(256) void conv_mfma(const short* __restrict__ xnh,
                                                 const short* __restrict__ wpk,
                                                 float* __restrict__ rot) {
    __shared__ short wlds[36864];
    const int tx = threadIdx.x, ty = threadIdx.y;
    const int tid = ty * 64 + tx;
    for (int i = tid; i < 4608; i += 256)        // 4608*16B = 73728B
        ((bf16x8*)wlds)[i] = ((const bf16x8*)wpk)[i];
    __syncthreads();

    const int ntile = blockIdx.x * 4 + ty;       // 0..2303
    const int b   = ntile / 576;
    const int hw0 = (ntile % 576) * 16;
    const int h   = hw0 / Wdim;
    const int w0  = hw0 % Wdim;
    const int px = tx & 15, kg = tx >> 4;

    f32x4 acc0 = {0.f, 0.f, 0.f, 0.f};
    f32x4 acc1 = {0.f, 0.f, 0.f, 0.f};
    const short* xb = xnh + (((size_t)b * 98 + h) * 98 + (w0 + px)) * 128 + kg * 8;
    const short* wl = wlds + tx * 8;

#pragma unroll
    for (int tap = 0; tap < 9; ++tap) {
        const int di = tap / 3, dj = tap % 3;
        const short* xr = xb + (di * 98 + dj) * 128;
#pragma unroll
        for (int ch = 0; ch < 4; ++ch) {
            bf16x8 bf = *(const bf16x8*)(xr + ch * 32);
            bf16x8 a0 = *(const bf16x8*)(wl + (tap * 4 + ch) * 512);
            bf16x8 a1 = *(const bf16x8*)(wl + ((9 + tap) * 4 + ch) * 512);
            acc0 = __builtin_amdgcn_mfma_f32_16x16x32_bf16(a0, bf, acc0, 0, 0, 0);
            acc1 = __builtin_amdgcn_mfma_f32_16x16x32_bf16(a1, bf, acc1, 0, 0, 0);
        }
    }

    // D: col = lane&15 = pixel, row = (lane>>4)*4 + reg = oc
    const int hwp = hw0 + px;
    float* rb = rot + (size_t)b * NOC * HW + hwp;
#pragma unroll
    for (int r = 0; r < 4; ++r)
        rb[(size_t)(kg * 4 + r) * HW] = acc0[r];
    if (kg == 0) {
        rb[(size_t)16 * HW] = acc1[0];
        rb[(size_t)17 * HW] = acc1[1];
    }
}

// ---------------------------------------------------------------------------
// Kernel 3: rot (+bias) -> bilinear coefficient quads.
// coefq[(b*9+t)*HW+hw] = (q00, q01, q10, float(h0*3+w0)); q11 = 1-q00-q01-q10.
// ---------------------------------------------------------------------------
__global__ __launch_bounds__(256) void coef_kernel(const float* __restrict__ rot,
                                                   const float* __restrict__ rot_b,
                                                   float4* __restrict__ coefq) {
    int idx = blockIdx.x * 256 + threadIdx.x;   // 0..36863
    int b  = idx / HW;
    int hw = idx % HW;
    int t0 = blockIdx.y * 3;
#pragma unroll
    for (int tt = 0; tt < 3; ++tt) {
        int t = t0 + tt;
        int i = t / 3, j = t % 3;
        float ch = rot[((size_t)b * NOC + 2 * t + 0) * HW + hw] + rot_b[2 * t + 0] + (0.5f + (float)i);
        float cw = rot[((size_t)b * NOC + 2 * t + 1) * HW + hw] + rot_b[2 * t + 1] + (0.5f + (float)j);
        ch = fminf(fmaxf(ch, 0.f), 3.f);
        cw = fminf(fmaxf(cw, 0.f), 3.f);
        float h0f = floorf(ch), w0f = floorf(cw);
        float lh = ch - h0f, lw = cw - w0f;
        int h0 = (int)h0f, w0 = (int)w0f;
        float bh0 = 1.f - lh;
        float aw0 = 1.f - lw;
        if (h0 >= 3) { h0 = 2; bh0 = 0.f; }
        if (w0 >= 3) { w0 = 2; aw0 = 0.f; }
        float4 cf;
        cf.x = aw0 * bh0;                 // q00 -> W[h0][w0]
        cf.y = (1.f - aw0) * bh0;         // q01 -> W[h0][w0+1]
        cf.z = aw0 * (1.f - bh0);         // q10 -> W[h0+1][w0]
        cf.w = (float)(h0 * 3 + w0);      // table index
        coefq[(size_t)(b * 9 + t) * HW + hw] = cf;
    }
}

// ---------------------------------------------------------------------------
// Kernel 4: apply. Thread = 1 pixel, loops 32 channels (ty picks c-range).
// Per-c packed bilinear quad table wq[c][9] (float4) in LDS, one b128 per tap.
// ---------------------------------------------------------------------------
__global__ __launch_bounds__(256) void apply_kernel(const float* __restrict__ xpad,
                                                    const float4* __restrict__ coefq,
                                                    const float* __restrict__ weight,
                                                    float* __restrict__ out) {
    __shared__ float4 wq[Cdim * 9];
    int tid = threadIdx.y * 64 + threadIdx.x;
    for (int i = tid; i < Cdim * 9; i += 256) {
        int c = i / 9, t = i - c * 9;
        int r = t / 3, s = t - r * 3;
        const float* wb = weight + (size_t)c * 16 + r * 4 + s;
        wq[i] = make_float4(wb[0], wb[1], wb[4], wb[5]);
    }
    __syncthreads();

    int px = blockIdx.x * 64 + threadIdx.x;   // 0..36863
    int b  = px / HW;
    int hw = px % HW;
    int h  = hw / Wdim;
    int wc = hw % Wdim;

    float q00[9], q01[9], q10[9], q11[9];
    int lidx[9];
#pragma unroll
    for (int t = 0; t < 9; ++t) {
        float4 cf = coefq[(size_t)(b * 9 + t) * HW + hw];
        q00[t] = cf.x;
        q01[t] = cf.y;
        q10[t] = cf.z;
        q11[t] = 1.f - cf.x - cf.y - cf.z;
        lidx[t] = (int)cf.w;
    }

    int c0 = threadIdx.y * 32;
    // tap (di,dj) reads true (h+di-1, w+dj-1) -> padded (h+di, w+dj+2)
    const float* xb = xpad + ((size_t)(b * Cdim + c0) * PADH + h) * PADW + (wc + 2);
    float* ob = out + ((size_t)(b * Cdim + c0)) * HW + hw;

#pragma unroll 2
    for (int k = 0; k < 32; ++k) {
        int c = c0 + k;
        float acc = 0.f;
#pragma unroll
        for (int t = 0; t < 9; ++t) {
            float4 g = wq[c * 9 + lidx[t]];
            float ws = q00[t] * g.x;
            ws = fmaf(q01[t], g.y, ws);
            ws = fmaf(q10[t], g.z, ws);
            ws = fmaf(q11[t], g.w, ws);
            acc = fmaf(ws, xb[(t / 3) * PADW + (t % 3)], acc);
        }
        ob[(size_t)k * HW] = acc;
        xb += (size_t)PADH * PADW;
    }
}

// ---------------------------------------------------------------------------
extern "C" void kernel_launch(void* const* d_in, const int* in_sizes, int n_in,
                              void* d_out, int out_size, void* d_ws, size_t ws_size,
                              hipStream_t stream) {
    const float* x      = (const float*)d_in[0];
    const float* rot_w  = (const float*)d_in[1];
    const float* rot_b  = (const float*)d_in[2];
    const float* weight = (const float*)d_in[3];
    float* out = (float*)d_out;

    char* ws = (char*)d_ws;
    // all sizes already 256B-aligned
    const size_t xpad_bytes = (size_t)Bdim * Cdim * PADH * PADW * 4;   // 20,873,216
    const size_t xnh_bytes  = (size_t)Bdim * 98 * 98 * 128 * 2;        //  9,834,496
    const size_t wpk_bytes  = (size_t)2 * 9 * 4 * 64 * 8 * 2;          //     73,728
    const size_t rot_bytes  = (size_t)Bdim * NOC * HW * 4;             //  2,654,208

    float* xpad  = (float*)ws;
    short* xnh   = (short*)(ws + xpad_bytes);
    short* wpk   = (short*)(ws + xpad_bytes + xnh_bytes);
    float* rot   = (float*)(ws + xpad_bytes + xnh_bytes + wpk_bytes);
    float4* coefq = (float4*)(ws + xpad_bytes + xnh_bytes + wpk_bytes + rot_bytes);

    prep_kernel<<<1432, 256, 0, stream>>>(x, rot_w, xpad, xnh, wpk);
    conv_mfma<<<576, dim3(64, 4), 0, stream>>>(xnh, wpk, rot);
    coef_kernel<<<dim3(Bdim * HW / 256, 3), 256, 0, stream>>>(rot, rot_b, coefq);
    apply_kernel<<<dim3(Bdim * HW / 64), dim3(64, 4), 0, stream>>>(xpad, coefq, weight, out);
}